// Round 4
// baseline (297.784 us; speedup 1.0000x reference)
//
#include <hip/hip_runtime.h>
#include <math.h>

// Problem constants (B=2, N=512, C=256, OUT=256, H=4, hd=64)
#define NB    2
#define NN    512
#define CC    256
#define OUTC  256
#define HH    4
#define LN_EPS 1e-5f

// ---------------------------------------------------------------------------
// Kernel A: row precompute  hi = x@We[:C]+be, hj = x@We[C:], v = x@Wv+bv
// grid 256 blocks (4 rows each), 256 threads (thread = output channel)
// ---------------------------------------------------------------------------
__global__ __launch_bounds__(256) void kA(
    const float* __restrict__ x,  const float* __restrict__ We,
    const float* __restrict__ be, const float* __restrict__ Wv,
    const float* __restrict__ bv,
    float* __restrict__ hi, float* __restrict__ hj, float* __restrict__ v)
{
    __shared__ __align__(16) float xs[4][CC];
    const int r0 = blockIdx.x * 4;
    const int t  = threadIdx.x;
    #pragma unroll
    for (int k = 0; k < 4; ++k)
        xs[k][t] = x[(size_t)(r0 + k) * CC + t];
    __syncthreads();

    float ai[4] = {0,0,0,0}, aj[4] = {0,0,0,0}, av[4] = {0,0,0,0};
    for (int c = 0; c < CC; ++c) {
        float we0 = We[(size_t)c * OUTC + t];
        float we1 = We[(size_t)(CC + c) * OUTC + t];
        float wv  = Wv[(size_t)c * OUTC + t];
        #pragma unroll
        for (int k = 0; k < 4; ++k) {
            float xv = xs[k][c];
            ai[k] = fmaf(xv, we0, ai[k]);
            aj[k] = fmaf(xv, we1, aj[k]);
            av[k] = fmaf(xv, wv , av[k]);
        }
    }
    float beT = be[t], bvT = bv[t];
    #pragma unroll
    for (int k = 0; k < 4; ++k) {
        hi[(size_t)(r0 + k) * OUTC + t] = ai[k] + beT;
        hj[(size_t)(r0 + k) * OUTC + t] = aj[k];
        v [(size_t)(r0 + k) * OUTC + t] = av[k] + bvT;
    }
}

// ---------------------------------------------------------------------------
// Kernel B: edge MLP  logits[b,i,j,h] = gelu(LN(hi_i + hj_j)) @ W2 + b2
// grid: 2 b x 128 itile x 8 jtile = 2048 blocks, 256 thr (4 waves)
// wave w -> i = itile*4+w ; lane l -> j = jtile*64+l (lane owns full pair)
// ---------------------------------------------------------------------------
__global__ __launch_bounds__(256) void kB(
    const float* __restrict__ hi,  const float* __restrict__ hj,
    const float* __restrict__ ln1g, const float* __restrict__ ln1b,
    const float* __restrict__ W2,  const float* __restrict__ b2,
    float* __restrict__ logits)
{
    __shared__ __align__(16) float his[4][CC];
    __shared__ __align__(16) float g1s[CC];
    __shared__ __align__(16) float b1s[CC];
    __shared__ __align__(16) float w2s[CC][HH];

    const int bid = blockIdx.x;
    const int jt  = (bid & 7) * 64;
    const int it  = ((bid >> 3) & 127) * 4;
    const int b   = bid >> 10;
    const int t   = threadIdx.x;

    #pragma unroll
    for (int k = 0; k < 4; ++k)
        his[k][t] = hi[(size_t)(b * NN + it + k) * OUTC + t];
    g1s[t] = ln1g[t];
    b1s[t] = ln1b[t];
    #pragma unroll
    for (int k = 0; k < 4; ++k)
        ((float*)w2s)[t + 256 * k] = W2[t + 256 * k];
    __syncthreads();

    const int w = t >> 6, l = t & 63;
    const int i = it + w;
    const int j = jt + l;
    const float4* __restrict__ hj4p = (const float4*)(hj + (size_t)(b * NN + j) * OUTC);
    const float4* __restrict__ hi4p = (const float4*)(&his[w][0]);

    // pass 1: lane-local mean/var over 256 channels
    float s = 0.f, ss = 0.f;
    #pragma unroll 4
    for (int c4 = 0; c4 < 64; ++c4) {
        float4 a  = hi4p[c4];
        float4 bb = hj4p[c4];
        float e0 = a.x + bb.x, e1 = a.y + bb.y, e2 = a.z + bb.z, e3 = a.w + bb.w;
        s += (e0 + e1) + (e2 + e3);
        ss = fmaf(e0, e0, ss); ss = fmaf(e1, e1, ss);
        ss = fmaf(e2, e2, ss); ss = fmaf(e3, e3, ss);
    }
    const float mu  = s * (1.f / 256.f);
    const float var = fmaf(ss, 1.f / 256.f, -mu * mu);
    const float rs  = rsqrtf(var + LN_EPS);
    const float nmurs = -mu * rs;

    // pass 2: normalize -> gelu(exact) -> dot W2
    float p0 = 0.f, p1 = 0.f, p2 = 0.f, p3 = 0.f;
    #pragma unroll 2
    for (int c4 = 0; c4 < 64; ++c4) {
        float4 a  = hi4p[c4];
        float4 bb = hj4p[c4];
        float4 g  = ((const float4*)g1s)[c4];
        float4 be_ = ((const float4*)b1s)[c4];
        const float4* w2r = (const float4*)&w2s[c4 * 4][0];
        {
            float n = fmaf(a.x + bb.x, rs, nmurs);
            n = fmaf(n, g.x, be_.x);
            float ge = 0.5f * n * (1.f + erff(n * 0.70710678118654752f));
            float4 wr = w2r[0];
            p0 = fmaf(ge, wr.x, p0); p1 = fmaf(ge, wr.y, p1);
            p2 = fmaf(ge, wr.z, p2); p3 = fmaf(ge, wr.w, p3);
        }
        {
            float n = fmaf(a.y + bb.y, rs, nmurs);
            n = fmaf(n, g.y, be_.y);
            float ge = 0.5f * n * (1.f + erff(n * 0.70710678118654752f));
            float4 wr = w2r[1];
            p0 = fmaf(ge, wr.x, p0); p1 = fmaf(ge, wr.y, p1);
            p2 = fmaf(ge, wr.z, p2); p3 = fmaf(ge, wr.w, p3);
        }
        {
            float n = fmaf(a.z + bb.z, rs, nmurs);
            n = fmaf(n, g.z, be_.z);
            float ge = 0.5f * n * (1.f + erff(n * 0.70710678118654752f));
            float4 wr = w2r[2];
            p0 = fmaf(ge, wr.x, p0); p1 = fmaf(ge, wr.y, p1);
            p2 = fmaf(ge, wr.z, p2); p3 = fmaf(ge, wr.w, p3);
        }
        {
            float n = fmaf(a.w + bb.w, rs, nmurs);
            n = fmaf(n, g.w, be_.w);
            float ge = 0.5f * n * (1.f + erff(n * 0.70710678118654752f));
            float4 wr = w2r[3];
            p0 = fmaf(ge, wr.x, p0); p1 = fmaf(ge, wr.y, p1);
            p2 = fmaf(ge, wr.z, p2); p3 = fmaf(ge, wr.w, p3);
        }
    }
    float4 b2v = *(const float4*)b2;
    float4 outv = make_float4(p0 + b2v.x, p1 + b2v.y, p2 + b2v.z, p3 + b2v.w);
    ((float4*)logits)[(size_t)(b * NN + i) * NN + j] = outv;
}

// ---------------------------------------------------------------------------
// Kernel C: softmax over j + PV einsum + Wo + residual + LN2
// grid: 2 b x 128 itile = 256 blocks, 256 thr
// ---------------------------------------------------------------------------
__global__ __launch_bounds__(256) void kC(
    const float* __restrict__ logits, const float* __restrict__ v,
    const float* __restrict__ Wo,     const float* __restrict__ bo,
    const float* __restrict__ x,      const float* __restrict__ g2,
    const float* __restrict__ b2ln,   float* __restrict__ out)
{
    __shared__ __align__(16) float wl[4 * NN * HH];   // 32 KB: logits then weights
    __shared__ __align__(16) float sm[4][HH][2];      // [i][h] -> {max, 1/sum}
    __shared__ __align__(16) float out1[4][OUTC];     // PV result
    __shared__ float redb[4][4][2];                   // LN2 wave partials

    const int bid = blockIdx.x;
    const int b   = bid >> 7;
    const int it  = (bid & 127) * 4;
    const int t   = threadIdx.x;

    // stage logits for 4 i's: 8192 floats
    {
        const float4* src = (const float4*)logits + (size_t)(b * NN + it) * NN;
        float4* dst = (float4*)wl;
        #pragma unroll
        for (int k = 0; k < 8; ++k) dst[t + 256 * k] = src[t + 256 * k];
    }
    __syncthreads();

    // softmax stats: 16 (i,h) tasks x 16 threads
    {
        const int g = t >> 4, k = t & 15;
        const int i = g >> 2, h = g & 3;
        const float* base = wl + i * (NN * HH) + h;
        float m = -1e30f;
        for (int jj = 0; jj < 32; ++jj) m = fmaxf(m, base[(k * 32 + jj) * 4]);
        #pragma unroll
        for (int off = 1; off < 16; off <<= 1) m = fmaxf(m, __shfl_xor(m, off));
        float ssum = 0.f;
        for (int jj = 0; jj < 32; ++jj) ssum += __expf(base[(k * 32 + jj) * 4] - m);
        #pragma unroll
        for (int off = 1; off < 16; off <<= 1) ssum += __shfl_xor(ssum, off);
        if (k == 0) { sm[i][h][0] = m; sm[i][h][1] = 1.f / ssum; }
    }
    __syncthreads();

    // convert logits -> softmax weights in place
    {
        #pragma unroll 4
        for (int k = 0; k < 32; ++k) {
            int idx = t + 256 * k;
            int i = idx >> 11, h = idx & 3;
            wl[idx] = __expf(wl[idx] - sm[i][h][0]) * sm[i][h][1];
        }
    }
    __syncthreads();

    // PV: out1[i][c] = sum_j w[i][j][h(c)] * v[b,j,c]
    {
        const int h = t >> 6;  // wave-uniform
        float a0 = 0.f, a1 = 0.f, a2 = 0.f, a3 = 0.f;
        const float* vb = v + (size_t)b * NN * OUTC + t;
        for (int j = 0; j < NN; ++j) {
            float vv = vb[(size_t)j * OUTC];
            a0 = fmaf(wl[0 * 2048 + j * 4 + h], vv, a0);
            a1 = fmaf(wl[1 * 2048 + j * 4 + h], vv, a1);
            a2 = fmaf(wl[2 * 2048 + j * 4 + h], vv, a2);
            a3 = fmaf(wl[3 * 2048 + j * 4 + h], vv, a3);
        }
        out1[0][t] = a0; out1[1][t] = a1; out1[2][t] = a2; out1[3][t] = a3;
    }
    __syncthreads();

    // Wo matvec + bias + residual, then LN2 per i
    {
        float a0 = bo[t], a1 = a0, a2 = a0, a3 = a0;
        for (int c = 0; c < OUTC; ++c) {
            float wv = Wo[(size_t)c * OUTC + t];
            a0 = fmaf(out1[0][c], wv, a0);
            a1 = fmaf(out1[1][c], wv, a1);
            a2 = fmaf(out1[2][c], wv, a2);
            a3 = fmaf(out1[3][c], wv, a3);
        }
        float r[4];
        r[0] = a0 + x[(size_t)(b * NN + it + 0) * OUTC + t];
        r[1] = a1 + x[(size_t)(b * NN + it + 1) * OUTC + t];
        r[2] = a2 + x[(size_t)(b * NN + it + 2) * OUTC + t];
        r[3] = a3 + x[(size_t)(b * NN + it + 3) * OUTC + t];

        const int w = t >> 6, l = t & 63;
        #pragma unroll
        for (int i = 0; i < 4; ++i) {
            float sv = r[i], sq = r[i] * r[i];
            #pragma unroll
            for (int off = 1; off < 64; off <<= 1) {
                sv += __shfl_xor(sv, off);
                sq += __shfl_xor(sq, off);
            }
            if (l == 0) { redb[w][i][0] = sv; redb[w][i][1] = sq; }
        }
        __syncthreads();
        float gg = g2[t], bb = b2ln[t];
        #pragma unroll
        for (int i = 0; i < 4; ++i) {
            float sv = redb[0][i][0] + redb[1][i][0] + redb[2][i][0] + redb[3][i][0];
            float sq = redb[0][i][1] + redb[1][i][1] + redb[2][i][1] + redb[3][i][1];
            float mu  = sv * (1.f / 256.f);
            float var = sq * (1.f / 256.f) - mu * mu;
            float rsi = rsqrtf(var + LN_EPS);
            out[(size_t)(b * NN + it + i) * OUTC + t] = (r[i] - mu) * rsi * gg + bb;
        }
    }
}

// ---------------------------------------------------------------------------
extern "C" void kernel_launch(void* const* d_in, const int* in_sizes, int n_in,
                              void* d_out, int out_size, void* d_ws, size_t ws_size,
                              hipStream_t stream) {
    (void)in_sizes; (void)n_in; (void)out_size; (void)ws_size;
    const float* x    = (const float*)d_in[0];
    const float* We   = (const float*)d_in[1];
    const float* be   = (const float*)d_in[2];
    const float* ln1g = (const float*)d_in[3];
    const float* ln1b = (const float*)d_in[4];
    const float* W2   = (const float*)d_in[5];
    const float* b2   = (const float*)d_in[6];
    const float* Wv   = (const float*)d_in[7];
    const float* bv   = (const float*)d_in[8];
    const float* Wo   = (const float*)d_in[9];
    const float* bo   = (const float*)d_in[10];
    const float* ln2g = (const float*)d_in[11];
    const float* ln2b = (const float*)d_in[12];
    float* out = (float*)d_out;

    float* ws = (float*)d_ws;
    float* hi     = ws;                 // 1024*256
    float* hj     = ws + 262144;        // 1024*256
    float* v      = ws + 524288;        // 1024*256
    float* logits = ws + 786432;        // 2*512*512*4 = 2097152

    kA<<<256,  256, 0, stream>>>(x, We, be, Wv, bv, hi, hj, v);
    kB<<<2048, 256, 0, stream>>>(hi, hj, ln1g, ln1b, W2, b2, logits);
    kC<<<256,  256, 0, stream>>>(logits, v, Wo, bo, x, ln2g, ln2b, out);
}

// Round 5
// 274.446 us; speedup vs baseline: 1.0850x; 1.0850x over previous
//
#include <hip/hip_runtime.h>
#include <math.h>

// Problem constants (B=2, N=512, C=256, OUT=256, H=4, hd=64)
#define NB    2
#define NN    512
#define CC    256
#define OUTC  256
#define HH    4
#define LN_EPS 1e-5f

// ---------------------------------------------------------------------------
// Fast GELU (tanh/sigmoid form): x * sigmoid(1.5957691*(x + 0.044715*x^3))
// = exp2-based: e = exp2(x * (c3*x^2 + c1)), ge = x / (1 + e)
//   c1 = -1.5957691216 * log2(e) = -2.3022077
//   c3 = c1 * 0.044715          = -0.1029432
// 5 VALU + v_exp_f32 + v_rcp_f32. Max abs err vs exact-erf gelu ~3e-3.
// ---------------------------------------------------------------------------
__device__ __forceinline__ float gelu_fast(float x) {
    float s   = x * x;
    float w   = fmaf(-0.1029432f, s, -2.3022077f);
    float e   = exp2f(x * w);
    float ge  = x * __builtin_amdgcn_rcpf(1.0f + e);
    return ge;
}

// ---------------------------------------------------------------------------
// Kernel A: row precompute  hi = x@We[:C]+be, hj = x@We[C:], v = x@Wv+bv
// grid 256 blocks (4 rows each), 256 threads (thread = output channel)
// ---------------------------------------------------------------------------
__global__ __launch_bounds__(256) void kA(
    const float* __restrict__ x,  const float* __restrict__ We,
    const float* __restrict__ be, const float* __restrict__ Wv,
    const float* __restrict__ bv,
    float* __restrict__ hi, float* __restrict__ hj, float* __restrict__ v)
{
    __shared__ __align__(16) float xs[4][CC];
    const int r0 = blockIdx.x * 4;
    const int t  = threadIdx.x;
    #pragma unroll
    for (int k = 0; k < 4; ++k)
        xs[k][t] = x[(size_t)(r0 + k) * CC + t];
    __syncthreads();

    float ai[4] = {0,0,0,0}, aj[4] = {0,0,0,0}, av[4] = {0,0,0,0};
    for (int c = 0; c < CC; ++c) {
        float we0 = We[(size_t)c * OUTC + t];
        float we1 = We[(size_t)(CC + c) * OUTC + t];
        float wv  = Wv[(size_t)c * OUTC + t];
        #pragma unroll
        for (int k = 0; k < 4; ++k) {
            float xv = xs[k][c];
            ai[k] = fmaf(xv, we0, ai[k]);
            aj[k] = fmaf(xv, we1, aj[k]);
            av[k] = fmaf(xv, wv , av[k]);
        }
    }
    float beT = be[t], bvT = bv[t];
    #pragma unroll
    for (int k = 0; k < 4; ++k) {
        hi[(size_t)(r0 + k) * OUTC + t] = ai[k] + beT;
        hj[(size_t)(r0 + k) * OUTC + t] = aj[k];
        v [(size_t)(r0 + k) * OUTC + t] = av[k] + bvT;
    }
}

// ---------------------------------------------------------------------------
// Kernel B: edge MLP  logits[b,i,j,h] = gelu(LN(hi_i + hj_j)) @ W2 + b2
// grid: 2 b x 128 itile x 8 jtile = 2048 blocks, 256 thr (4 waves)
// wave w -> i = itile*4+w ; lane l -> j = jtile*64+l (lane owns full pair)
// ---------------------------------------------------------------------------
__global__ __launch_bounds__(256) void kB(
    const float* __restrict__ hi,  const float* __restrict__ hj,
    const float* __restrict__ ln1g, const float* __restrict__ ln1b,
    const float* __restrict__ W2,  const float* __restrict__ b2,
    float* __restrict__ logits)
{
    __shared__ __align__(16) float his[4][CC];
    __shared__ __align__(16) float g1s[CC];
    __shared__ __align__(16) float b1s[CC];
    __shared__ __align__(16) float w2s[CC][HH];

    const int bid = blockIdx.x;
    const int jt  = (bid & 7) * 64;
    const int it  = ((bid >> 3) & 127) * 4;
    const int b   = bid >> 10;
    const int t   = threadIdx.x;

    #pragma unroll
    for (int k = 0; k < 4; ++k)
        his[k][t] = hi[(size_t)(b * NN + it + k) * OUTC + t];
    g1s[t] = ln1g[t];
    b1s[t] = ln1b[t];
    #pragma unroll
    for (int k = 0; k < 4; ++k)
        ((float*)w2s)[t + 256 * k] = W2[t + 256 * k];
    __syncthreads();

    const int w = t >> 6, l = t & 63;
    const int i = it + w;
    const int j = jt + l;
    const float4* __restrict__ hj4p = (const float4*)(hj + (size_t)(b * NN + j) * OUTC);
    const float4* __restrict__ hi4p = (const float4*)(&his[w][0]);

    // pass 1: lane-local mean/var over 256 channels
    float s = 0.f, ss = 0.f;
    #pragma unroll 4
    for (int c4 = 0; c4 < 64; ++c4) {
        float4 a  = hi4p[c4];
        float4 bb = hj4p[c4];
        float e0 = a.x + bb.x, e1 = a.y + bb.y, e2 = a.z + bb.z, e3 = a.w + bb.w;
        s += (e0 + e1) + (e2 + e3);
        ss = fmaf(e0, e0, ss); ss = fmaf(e1, e1, ss);
        ss = fmaf(e2, e2, ss); ss = fmaf(e3, e3, ss);
    }
    const float mu  = s * (1.f / 256.f);
    const float var = fmaf(ss, 1.f / 256.f, -mu * mu);
    const float rs  = rsqrtf(var + LN_EPS);
    const float nmurs = -mu * rs;

    // pass 2: normalize -> gelu(fast) -> dot W2
    float p0 = 0.f, p1 = 0.f, p2 = 0.f, p3 = 0.f;
    #pragma unroll 4
    for (int c4 = 0; c4 < 64; ++c4) {
        float4 a  = hi4p[c4];
        float4 bb = hj4p[c4];
        float4 g  = ((const float4*)g1s)[c4];
        float4 be_ = ((const float4*)b1s)[c4];
        const float4* w2r = (const float4*)&w2s[c4 * 4][0];
        {
            float n = fmaf(a.x + bb.x, rs, nmurs);
            n = fmaf(n, g.x, be_.x);
            float ge = gelu_fast(n);
            float4 wr = w2r[0];
            p0 = fmaf(ge, wr.x, p0); p1 = fmaf(ge, wr.y, p1);
            p2 = fmaf(ge, wr.z, p2); p3 = fmaf(ge, wr.w, p3);
        }
        {
            float n = fmaf(a.y + bb.y, rs, nmurs);
            n = fmaf(n, g.y, be_.y);
            float ge = gelu_fast(n);
            float4 wr = w2r[1];
            p0 = fmaf(ge, wr.x, p0); p1 = fmaf(ge, wr.y, p1);
            p2 = fmaf(ge, wr.z, p2); p3 = fmaf(ge, wr.w, p3);
        }
        {
            float n = fmaf(a.z + bb.z, rs, nmurs);
            n = fmaf(n, g.z, be_.z);
            float ge = gelu_fast(n);
            float4 wr = w2r[2];
            p0 = fmaf(ge, wr.x, p0); p1 = fmaf(ge, wr.y, p1);
            p2 = fmaf(ge, wr.z, p2); p3 = fmaf(ge, wr.w, p3);
        }
        {
            float n = fmaf(a.w + bb.w, rs, nmurs);
            n = fmaf(n, g.w, be_.w);
            float ge = gelu_fast(n);
            float4 wr = w2r[3];
            p0 = fmaf(ge, wr.x, p0); p1 = fmaf(ge, wr.y, p1);
            p2 = fmaf(ge, wr.z, p2); p3 = fmaf(ge, wr.w, p3);
        }
    }
    float4 b2v = *(const float4*)b2;
    float4 outv = make_float4(p0 + b2v.x, p1 + b2v.y, p2 + b2v.z, p3 + b2v.w);
    ((float4*)logits)[(size_t)(b * NN + i) * NN + j] = outv;
}

// ---------------------------------------------------------------------------
// Kernel C: softmax over j + PV einsum + Wo + residual + LN2
// grid: 2 b x 128 itile = 256 blocks, 256 thr
// ---------------------------------------------------------------------------
__global__ __launch_bounds__(256) void kC(
    const float* __restrict__ logits, const float* __restrict__ v,
    const float* __restrict__ Wo,     const float* __restrict__ bo,
    const float* __restrict__ x,      const float* __restrict__ g2,
    const float* __restrict__ b2ln,   float* __restrict__ out)
{
    __shared__ __align__(16) float wl[4 * NN * HH];   // 32 KB: logits then weights
    __shared__ __align__(16) float sm[4][HH][2];      // [i][h] -> {max, 1/sum}
    __shared__ __align__(16) float out1[4][OUTC];     // PV result
    __shared__ float redb[4][4][2];                   // LN2 wave partials

    const int bid = blockIdx.x;
    const int b   = bid >> 7;
    const int it  = (bid & 127) * 4;
    const int t   = threadIdx.x;

    // stage logits for 4 i's: 8192 floats
    {
        const float4* src = (const float4*)logits + (size_t)(b * NN + it) * NN;
        float4* dst = (float4*)wl;
        #pragma unroll
        for (int k = 0; k < 8; ++k) dst[t + 256 * k] = src[t + 256 * k];
    }
    __syncthreads();

    // softmax stats: 16 (i,h) tasks x 16 threads
    {
        const int g = t >> 4, k = t & 15;
        const int i = g >> 2, h = g & 3;
        const float* base = wl + i * (NN * HH) + h;
        float m = -1e30f;
        for (int jj = 0; jj < 32; ++jj) m = fmaxf(m, base[(k * 32 + jj) * 4]);
        #pragma unroll
        for (int off = 1; off < 16; off <<= 1) m = fmaxf(m, __shfl_xor(m, off));
        float ssum = 0.f;
        for (int jj = 0; jj < 32; ++jj) ssum += __expf(base[(k * 32 + jj) * 4] - m);
        #pragma unroll
        for (int off = 1; off < 16; off <<= 1) ssum += __shfl_xor(ssum, off);
        if (k == 0) { sm[i][h][0] = m; sm[i][h][1] = 1.f / ssum; }
    }
    __syncthreads();

    // convert logits -> softmax weights in place
    {
        #pragma unroll 4
        for (int k = 0; k < 32; ++k) {
            int idx = t + 256 * k;
            int i = idx >> 11, h = idx & 3;
            wl[idx] = __expf(wl[idx] - sm[i][h][0]) * sm[i][h][1];
        }
    }
    __syncthreads();

    // PV: out1[i][c] = sum_j w[i][j][h(c)] * v[b,j,c]
    {
        const int h = t >> 6;  // wave-uniform
        float a0 = 0.f, a1 = 0.f, a2 = 0.f, a3 = 0.f;
        const float* vb = v + (size_t)b * NN * OUTC + t;
        for (int j = 0; j < NN; ++j) {
            float vv = vb[(size_t)j * OUTC];
            a0 = fmaf(wl[0 * 2048 + j * 4 + h], vv, a0);
            a1 = fmaf(wl[1 * 2048 + j * 4 + h], vv, a1);
            a2 = fmaf(wl[2 * 2048 + j * 4 + h], vv, a2);
            a3 = fmaf(wl[3 * 2048 + j * 4 + h], vv, a3);
        }
        out1[0][t] = a0; out1[1][t] = a1; out1[2][t] = a2; out1[3][t] = a3;
    }
    __syncthreads();

    // Wo matvec + bias + residual, then LN2 per i
    {
        float a0 = bo[t], a1 = a0, a2 = a0, a3 = a0;
        for (int c = 0; c < OUTC; ++c) {
            float wv = Wo[(size_t)c * OUTC + t];
            a0 = fmaf(out1[0][c], wv, a0);
            a1 = fmaf(out1[1][c], wv, a1);
            a2 = fmaf(out1[2][c], wv, a2);
            a3 = fmaf(out1[3][c], wv, a3);
        }
        float r[4];
        r[0] = a0 + x[(size_t)(b * NN + it + 0) * OUTC + t];
        r[1] = a1 + x[(size_t)(b * NN + it + 1) * OUTC + t];
        r[2] = a2 + x[(size_t)(b * NN + it + 2) * OUTC + t];
        r[3] = a3 + x[(size_t)(b * NN + it + 3) * OUTC + t];

        const int w = t >> 6, l = t & 63;
        #pragma unroll
        for (int i = 0; i < 4; ++i) {
            float sv = r[i], sq = r[i] * r[i];
            #pragma unroll
            for (int off = 1; off < 64; off <<= 1) {
                sv += __shfl_xor(sv, off);
                sq += __shfl_xor(sq, off);
            }
            if (l == 0) { redb[w][i][0] = sv; redb[w][i][1] = sq; }
        }
        __syncthreads();
        float gg = g2[t], bb = b2ln[t];
        #pragma unroll
        for (int i = 0; i < 4; ++i) {
            float sv = redb[0][i][0] + redb[1][i][0] + redb[2][i][0] + redb[3][i][0];
            float sq = redb[0][i][1] + redb[1][i][1] + redb[2][i][1] + redb[3][i][1];
            float mu  = sv * (1.f / 256.f);
            float var = sq * (1.f / 256.f) - mu * mu;
            float rsi = rsqrtf(var + LN_EPS);
            out[(size_t)(b * NN + it + i) * OUTC + t] = (r[i] - mu) * rsi * gg + bb;
        }
    }
}

// ---------------------------------------------------------------------------
extern "C" void kernel_launch(void* const* d_in, const int* in_sizes, int n_in,
                              void* d_out, int out_size, void* d_ws, size_t ws_size,
                              hipStream_t stream) {
    (void)in_sizes; (void)n_in; (void)out_size; (void)ws_size;
    const float* x    = (const float*)d_in[0];
    const float* We   = (const float*)d_in[1];
    const float* be   = (const float*)d_in[2];
    const float* ln1g = (const float*)d_in[3];
    const float* ln1b = (const float*)d_in[4];
    const float* W2   = (const float*)d_in[5];
    const float* b2   = (const float*)d_in[6];
    const float* Wv   = (const float*)d_in[7];
    const float* bv   = (const float*)d_in[8];
    const float* Wo   = (const float*)d_in[9];
    const float* bo   = (const float*)d_in[10];
    const float* ln2g = (const float*)d_in[11];
    const float* ln2b = (const float*)d_in[12];
    float* out = (float*)d_out;

    float* ws = (float*)d_ws;
    float* hi     = ws;                 // 1024*256
    float* hj     = ws + 262144;        // 1024*256
    float* v      = ws + 524288;        // 1024*256
    float* logits = ws + 786432;        // 2*512*512*4 = 2097152

    kA<<<256,  256, 0, stream>>>(x, We, be, Wv, bv, hi, hj, v);
    kB<<<2048, 256, 0, stream>>>(hi, hj, ln1g, ln1b, W2, b2, logits);
    kC<<<256,  256, 0, stream>>>(logits, v, Wo, bo, x, ln2g, ln2b, out);
}

// Round 7
// 224.544 us; speedup vs baseline: 1.3262x; 1.2222x over previous
//
#include <hip/hip_runtime.h>
#include <math.h>

// Problem constants (B=2, N=512, C=256, OUT=256, H=4, hd=64)
#define NB    2
#define NN    512
#define CC    256
#define OUTC  256
#define HH    4
#define LN_EPS 1e-5f

// Fast GELU (tanh/sigmoid form): 5 VALU + v_exp_f32 + v_rcp_f32, |err| ~3e-3
__device__ __forceinline__ float gelu_fast(float x) {
    float s   = x * x;
    float w   = fmaf(-0.1029432f, s, -2.3022077f);
    float e   = exp2f(x * w);
    return x * __builtin_amdgcn_rcpf(1.0f + e);
}

// ---------------------------------------------------------------------------
// Kernel A: row precompute  hi = x@We[:C]+be, hj = x@We[C:], v = x@Wv+bv
// ---------------------------------------------------------------------------
__global__ __launch_bounds__(256) void kA(
    const float* __restrict__ x,  const float* __restrict__ We,
    const float* __restrict__ be, const float* __restrict__ Wv,
    const float* __restrict__ bv,
    float* __restrict__ hi, float* __restrict__ hj, float* __restrict__ v)
{
    __shared__ __align__(16) float xs[4][CC];
    const int r0 = blockIdx.x * 4;
    const int t  = threadIdx.x;
    #pragma unroll
    for (int k = 0; k < 4; ++k)
        xs[k][t] = x[(size_t)(r0 + k) * CC + t];
    __syncthreads();

    float ai[4] = {0,0,0,0}, aj[4] = {0,0,0,0}, av[4] = {0,0,0,0};
    for (int c = 0; c < CC; ++c) {
        float we0 = We[(size_t)c * OUTC + t];
        float we1 = We[(size_t)(CC + c) * OUTC + t];
        float wv  = Wv[(size_t)c * OUTC + t];
        #pragma unroll
        for (int k = 0; k < 4; ++k) {
            float xv = xs[k][c];
            ai[k] = fmaf(xv, we0, ai[k]);
            aj[k] = fmaf(xv, we1, aj[k]);
            av[k] = fmaf(xv, wv , av[k]);
        }
    }
    float beT = be[t], bvT = bv[t];
    #pragma unroll
    for (int k = 0; k < 4; ++k) {
        hi[(size_t)(r0 + k) * OUTC + t] = ai[k] + beT;
        hj[(size_t)(r0 + k) * OUTC + t] = aj[k];
        v [(size_t)(r0 + k) * OUTC + t] = av[k] + bvT;
    }
}

// ---------------------------------------------------------------------------
// Kernel B v2: LDS-staged edge MLP.
// grid: 2 b x 64 itile(8) x 16 jtile(32) = 2048 blocks, 256 thr (4 waves).
// Tile: 8 i x 32 j = 256 pairs, one per thread.
// lane l of wave w: i = it + 2w + (l>>5), j = jt + (l&31).
// hj tile staged in LDS [32][260] (pad 4 floats -> b128 reads hit all 8
// bank-quads evenly = floor rate). hi tile [8][260]. One coalesced global
// read per tile; per-lane streaming is LDS-only (kills divergent-VMEM TA wall).
// ---------------------------------------------------------------------------
#define LDP 260
__global__ __launch_bounds__(256) void kB(
    const float* __restrict__ hi,  const float* __restrict__ hj,
    const float* __restrict__ ln1g, const float* __restrict__ ln1b,
    const float* __restrict__ W2,  const float* __restrict__ b2,
    float* __restrict__ logits)
{
    __shared__ __align__(16) float hjs[32][LDP];  // 33280 B
    __shared__ __align__(16) float his[8][LDP];   //  8320 B
    __shared__ __align__(16) float g1s[CC];       //  1024 B
    __shared__ __align__(16) float b1s[CC];       //  1024 B
    __shared__ __align__(16) float w2s[CC][HH];   //  4096 B  (total ~47.7 KB)

    const int bid = blockIdx.x;
    const int jt  = (bid & 15) * 32;
    const int it  = ((bid >> 4) & 63) * 8;
    const int b   = bid >> 10;
    const int t   = threadIdx.x;

    // stage hj tile: 32 rows = 2048 float4, coalesced
    {
        const float4* src = (const float4*)(hj + (size_t)(b * NN + jt) * OUTC);
        #pragma unroll
        for (int k = 0; k < 8; ++k) {
            int s   = k * 256 + t;
            int row = s >> 6, c4 = s & 63;
            *(float4*)&hjs[row][c4 * 4] = src[s];
        }
    }
    // stage hi tile: 8 rows = 512 float4, coalesced
    {
        const float4* src = (const float4*)(hi + (size_t)(b * NN + it) * OUTC);
        #pragma unroll
        for (int k = 0; k < 2; ++k) {
            int s   = k * 256 + t;
            int row = s >> 6, c4 = s & 63;
            *(float4*)&his[row][c4 * 4] = src[s];
        }
    }
    g1s[t] = ln1g[t];
    b1s[t] = ln1b[t];
    #pragma unroll
    for (int k = 0; k < 4; ++k)
        ((float*)w2s)[t + 256 * k] = W2[t + 256 * k];
    __syncthreads();

    const int w = t >> 6, l = t & 63;
    const int i = it + 2 * w + (l >> 5);
    const int j = jt + (l & 31);
    const float* __restrict__ hirow = &his[2 * w + (l >> 5)][0];
    const float* __restrict__ hjrow = &hjs[l & 31][0];

    // pass 1: lane-local mean/var over 256 channels (LDS reads only)
    float s = 0.f, ss = 0.f;
    #pragma unroll 4
    for (int c4 = 0; c4 < 64; ++c4) {
        float4 a  = *(const float4*)&hirow[c4 * 4];
        float4 bb = *(const float4*)&hjrow[c4 * 4];
        float e0 = a.x + bb.x, e1 = a.y + bb.y, e2 = a.z + bb.z, e3 = a.w + bb.w;
        s += (e0 + e1) + (e2 + e3);
        ss = fmaf(e0, e0, ss); ss = fmaf(e1, e1, ss);
        ss = fmaf(e2, e2, ss); ss = fmaf(e3, e3, ss);
    }
    const float mu  = s * (1.f / 256.f);
    const float var = fmaf(ss, 1.f / 256.f, -mu * mu);
    const float rs  = rsqrtf(var + LN_EPS);
    const float nmurs = -mu * rs;

    // pass 2: normalize -> gelu(fast) -> dot W2
    float p0 = 0.f, p1 = 0.f, p2 = 0.f, p3 = 0.f;
    #pragma unroll 4
    for (int c4 = 0; c4 < 64; ++c4) {
        float4 a  = *(const float4*)&hirow[c4 * 4];
        float4 bb = *(const float4*)&hjrow[c4 * 4];
        float4 g  = ((const float4*)g1s)[c4];
        float4 be_ = ((const float4*)b1s)[c4];
        const float4* w2r = (const float4*)&w2s[c4 * 4][0];
        {
            float n = fmaf(a.x + bb.x, rs, nmurs);
            n = fmaf(n, g.x, be_.x);
            float ge = gelu_fast(n);
            float4 wr = w2r[0];
            p0 = fmaf(ge, wr.x, p0); p1 = fmaf(ge, wr.y, p1);
            p2 = fmaf(ge, wr.z, p2); p3 = fmaf(ge, wr.w, p3);
        }
        {
            float n = fmaf(a.y + bb.y, rs, nmurs);
            n = fmaf(n, g.y, be_.y);
            float ge = gelu_fast(n);
            float4 wr = w2r[1];
            p0 = fmaf(ge, wr.x, p0); p1 = fmaf(ge, wr.y, p1);
            p2 = fmaf(ge, wr.z, p2); p3 = fmaf(ge, wr.w, p3);
        }
        {
            float n = fmaf(a.z + bb.z, rs, nmurs);
            n = fmaf(n, g.z, be_.z);
            float ge = gelu_fast(n);
            float4 wr = w2r[2];
            p0 = fmaf(ge, wr.x, p0); p1 = fmaf(ge, wr.y, p1);
            p2 = fmaf(ge, wr.z, p2); p3 = fmaf(ge, wr.w, p3);
        }
        {
            float n = fmaf(a.w + bb.w, rs, nmurs);
            n = fmaf(n, g.w, be_.w);
            float ge = gelu_fast(n);
            float4 wr = w2r[3];
            p0 = fmaf(ge, wr.x, p0); p1 = fmaf(ge, wr.y, p1);
            p2 = fmaf(ge, wr.z, p2); p3 = fmaf(ge, wr.w, p3);
        }
    }
    float4 b2v = *(const float4*)b2;
    float4 outv = make_float4(p0 + b2v.x, p1 + b2v.y, p2 + b2v.z, p3 + b2v.w);
    ((float4*)logits)[(size_t)(b * NN + i) * NN + j] = outv;
}

// ---------------------------------------------------------------------------
// Kernel C: softmax over j + PV einsum + Wo + residual + LN2
// grid: 2 b x 128 itile = 256 blocks, 256 thr
// ---------------------------------------------------------------------------
__global__ __launch_bounds__(256) void kC(
    const float* __restrict__ logits, const float* __restrict__ v,
    const float* __restrict__ Wo,     const float* __restrict__ bo,
    const float* __restrict__ x,      const float* __restrict__ g2,
    const float* __restrict__ b2ln,   float* __restrict__ out)
{
    __shared__ __align__(16) float wl[4 * NN * HH];
    __shared__ __align__(16) float sm[4][HH][2];
    __shared__ __align__(16) float out1[4][OUTC];
    __shared__ float redb[4][4][2];

    const int bid = blockIdx.x;
    const int b   = bid >> 7;
    const int it  = (bid & 127) * 4;
    const int t   = threadIdx.x;

    {
        const float4* src = (const float4*)logits + (size_t)(b * NN + it) * NN;
        float4* dst = (float4*)wl;
        #pragma unroll
        for (int k = 0; k < 8; ++k) dst[t + 256 * k] = src[t + 256 * k];
    }
    __syncthreads();

    {
        const int g = t >> 4, k = t & 15;
        const int i = g >> 2, h = g & 3;
        const float* base = wl + i * (NN * HH) + h;
        float m = -1e30f;
        for (int jj = 0; jj < 32; ++jj) m = fmaxf(m, base[(k * 32 + jj) * 4]);
        #pragma unroll
        for (int off = 1; off < 16; off <<= 1) m = fmaxf(m, __shfl_xor(m, off));
        float ssum = 0.f;
        for (int jj = 0; jj < 32; ++jj) ssum += __expf(base[(k * 32 + jj) * 4] - m);
        #pragma unroll
        for (int off = 1; off < 16; off <<= 1) ssum += __shfl_xor(ssum, off);
        if (k == 0) { sm[i][h][0] = m; sm[i][h][1] = 1.f / ssum; }
    }
    __syncthreads();

    {
        #pragma unroll 4
        for (int k = 0; k < 32; ++k) {
            int idx = t + 256 * k;
            int i = idx >> 11, h = idx & 3;
            wl[idx] = __expf(wl[idx] - sm[i][h][0]) * sm[i][h][1];
        }
    }
    __syncthreads();

    {
        const int h = t >> 6;
        float a0 = 0.f, a1 = 0.f, a2 = 0.f, a3 = 0.f;
        const float* vb = v + (size_t)b * NN * OUTC + t;
        for (int j = 0; j < NN; ++j) {
            float vv = vb[(size_t)j * OUTC];
            a0 = fmaf(wl[0 * 2048 + j * 4 + h], vv, a0);
            a1 = fmaf(wl[1 * 2048 + j * 4 + h], vv, a1);
            a2 = fmaf(wl[2 * 2048 + j * 4 + h], vv, a2);
            a3 = fmaf(wl[3 * 2048 + j * 4 + h], vv, a3);
        }
        out1[0][t] = a0; out1[1][t] = a1; out1[2][t] = a2; out1[3][t] = a3;
    }
    __syncthreads();

    {
        float a0 = bo[t], a1 = a0, a2 = a0, a3 = a0;
        for (int c = 0; c < OUTC; ++c) {
            float wv = Wo[(size_t)c * OUTC + t];
            a0 = fmaf(out1[0][c], wv, a0);
            a1 = fmaf(out1[1][c], wv, a1);
            a2 = fmaf(out1[2][c], wv, a2);
            a3 = fmaf(out1[3][c], wv, a3);
        }
        float r[4];
        r[0] = a0 + x[(size_t)(b * NN + it + 0) * OUTC + t];
        r[1] = a1 + x[(size_t)(b * NN + it + 1) * OUTC + t];
        r[2] = a2 + x[(size_t)(b * NN + it + 2) * OUTC + t];
        r[3] = a3 + x[(size_t)(b * NN + it + 3) * OUTC + t];

        const int w = t >> 6, l = t & 63;
        #pragma unroll
        for (int i = 0; i < 4; ++i) {
            float sv = r[i], sq = r[i] * r[i];
            #pragma unroll
            for (int off = 1; off < 64; off <<= 1) {
                sv += __shfl_xor(sv, off);
                sq += __shfl_xor(sq, off);
            }
            if (l == 0) { redb[w][i][0] = sv; redb[w][i][1] = sq; }
        }
        __syncthreads();
        float gg = g2[t], bb = b2ln[t];
        #pragma unroll
        for (int i = 0; i < 4; ++i) {
            float sv = redb[0][i][0] + redb[1][i][0] + redb[2][i][0] + redb[3][i][0];
            float sq = redb[0][i][1] + redb[1][i][1] + redb[2][i][1] + redb[3][i][1];
            float mu  = sv * (1.f / 256.f);
            float var = sq * (1.f / 256.f) - mu * mu;
            float rsi = rsqrtf(var + LN_EPS);
            out[(size_t)(b * NN + it + i) * OUTC + t] = (r[i] - mu) * rsi * gg + bb;
        }
    }
}

// ---------------------------------------------------------------------------
extern "C" void kernel_launch(void* const* d_in, const int* in_sizes, int n_in,
                              void* d_out, int out_size, void* d_ws, size_t ws_size,
                              hipStream_t stream) {
    (void)in_sizes; (void)n_in; (void)out_size; (void)ws_size;
    const float* x    = (const float*)d_in[0];
    const float* We   = (const float*)d_in[1];
    const float* be   = (const float*)d_in[2];
    const float* ln1g = (const float*)d_in[3];
    const float* ln1b = (const float*)d_in[4];
    const float* W2   = (const float*)d_in[5];
    const float* b2   = (const float*)d_in[6];
    const float* Wv   = (const float*)d_in[7];
    const float* bv   = (const float*)d_in[8];
    const float* Wo   = (const float*)d_in[9];
    const float* bo   = (const float*)d_in[10];
    const float* ln2g = (const float*)d_in[11];
    const float* ln2b = (const float*)d_in[12];
    float* out = (float*)d_out;

    float* ws = (float*)d_ws;
    float* hi     = ws;                 // 1024*256
    float* hj     = ws + 262144;        // 1024*256
    float* v      = ws + 524288;        // 1024*256
    float* logits = ws + 786432;        // 2*512*512*4

    kA<<<256,  256, 0, stream>>>(x, We, be, Wv, bv, hi, hj, v);
    kB<<<2048, 256, 0, stream>>>(hi, hj, ln1g, ln1b, W2, b2, logits);
    kC<<<256,  256, 0, stream>>>(logits, v, Wo, bo, x, ln2g, ln2b, out);
}